// Round 3
// baseline (691.266 us; speedup 1.0000x reference)
//
#include <hip/hip_runtime.h>
#include <hip/hip_bf16.h>

// word_choser: algebraically reduced. ALL float tensors are FLOAT32 (per the
// reference dtypes) — rounds 1-2 failed with NaN because f32 buffers were read
// as bf16 (low mantissa halves reinterpret to exp=0xFF -> NaN).
//
//  t = colsum(hiddens)                       [D]
//  m = (t @ dim_up + cur_h) / (S+1)          [D]   (mean over node embs)
//  v = relu(m @ W_gcn)                       [D]   (all GCN rows identical)
//  softmax over identical scores is uniform -> att_result = v (att_w dead)
//  g = v @ dim_down                          [D]
//  gates[r] = Wi[r][0:D]·sen + Wi[r][D:2D]·g + Wi[r][2D]*pos + bi + Wh[r]·cur_h + bh
//  new_h = o * tanh(f*cur_cell + i*tanh(g_gate))   [D]
//  out = new_h @ dim_out                     [NTOK]

#define DD    2048
#define NTOK  32000
#define INPD  4097
#define INV_N (1.0f/4097.0f)

// ws layout (floats), total 32768 floats = 128 KiB
#define WS_PT 0        // partial_t [8][2048]  (non-atomic, one writer per slot)
#define WS_GB 16384    // gate_base [8192]
#define WS_M  24576    // t@dim_up accumulator [2048]   (atomic, zeroed by K1)
#define WS_V  26624    // m@W_gcn accumulator  [2048]   (atomic, zeroed by K1)
#define WS_G  28672    // v@dim_down accumulator [2048] (atomic, zeroed by K1)
#define WS_NH 30720    // new_h [2048]

// K1: blocks 0..255: gate_base rows (Wi first half + Wh + bias + pos term)
//     blocks 256..319: column-sum partials of hiddens
//     block 256 additionally zeroes the three atomic accumulators (consumed
//     only by later kernels in the stream, so no intra-kernel race).
__global__ __launch_bounds__(256) void k1_base(
    const float* __restrict__ sen, const float* __restrict__ hid,
    const int* __restrict__ posp,
    const float* __restrict__ Wi, const float* __restrict__ Wh,
    const float* __restrict__ bi, const float* __restrict__ bh,
    const float* __restrict__ curh, float* __restrict__ ws)
{
    __shared__ float sen_lds[DD];
    __shared__ float ch_lds[DD];
    const int t = threadIdx.x;
    const int b = blockIdx.x;
    const int wv = t >> 6, lane = t & 63;
    if (b < 256) {
        for (int k = 0; k < 8; ++k) {
            int idx = t + k*256;
            sen_lds[idx] = sen[idx];
            ch_lds[idx]  = curh[idx];
        }
        __syncthreads();
        float posf = (float)(*posp);
        for (int i = 0; i < 8; ++i) {
            int r = b*32 + wv*8 + i;                 // r = gate*2048 + d
            const float*  wir = Wi + (size_t)r * INPD;        // 4B aligned only
            const float4* whr = (const float4*)(Wh + (size_t)r * DD); // 16B aligned
            float acc = 0.f;
            #pragma unroll
            for (int k = 0; k < 32; ++k) {
                int c = k*64 + lane;
                acc += wir[c] * sen_lds[c];
            }
            #pragma unroll
            for (int k = 0; k < 8; ++k) {
                float4 q = whr[k*64 + lane];
                int cb = k*256 + lane*4;
                acc += q.x*ch_lds[cb+0] + q.y*ch_lds[cb+1]
                     + q.z*ch_lds[cb+2] + q.w*ch_lds[cb+3];
            }
            if (lane == 0)
                acc += posf * wir[4096] + bi[r] + bh[r];
            #pragma unroll
            for (int off = 32; off > 0; off >>= 1) acc += __shfl_down(acc, off, 64);
            if (lane == 0) ws[WS_GB + r] = acc;
        }
    } else {
        if (b == 256) {
            // zero WS_M / WS_V / WS_G (3 * 2048 floats, contiguous)
            for (int k = 0; k < 24; ++k) ws[WS_M + t + k*256] = 0.f;
        }
        int ww = (b - 256)*4 + wv;                   // 256 wave tasks
        int dg = ww & 31, rc = ww >> 5;
        int d = dg*64 + lane;
        const float* hp = hid + (size_t)(rc*512) * DD + d;
        float acc = 0.f;
        #pragma unroll 8
        for (int k = 0; k < 512; ++k) acc += hp[(size_t)k * DD];
        ws[WS_PT + rc*2048 + d] = acc;
    }
}

// K2/K3/K4: y += x @ M (M row-major DxD f32), atomic f32 accumulation into a
// 2048-float vector. 256 one-wave blocks: jg(4) x ic(64); each block handles
// rows [ic*32, ic*32+32) x columns [jg*512, jg*512+512).
// MODE 0: x = t            (sum of 8 partial_t chunks)        -> WS_M
// MODE 1: x = (WS_M+ch)/N                                     -> WS_V
// MODE 2: x = relu(WS_V)                                      -> WS_G
template<int MODE>
__global__ __launch_bounds__(64) void k_mv(const float* __restrict__ M,
                                           const float* __restrict__ curh,
                                           float* __restrict__ ws)
{
    const int b = blockIdx.x;
    const int lane = threadIdx.x;
    const int jg = b & 3, ic = b >> 2;
    const int i0 = ic * 32;
    const int js = jg*512 + lane*8;
    float xv = 0.f;
    if (lane < 32) {
        int i = i0 + lane;
        if (MODE == 0) {
            #pragma unroll
            for (int c = 0; c < 8; ++c) xv += ws[WS_PT + c*2048 + i];
        } else if (MODE == 1) {
            xv = (ws[WS_M + i] + curh[i]) * INV_N;
        } else {
            xv = fmaxf(ws[WS_V + i], 0.f);
        }
    }
    float acc[8];
    #pragma unroll
    for (int k = 0; k < 8; ++k) acc[k] = 0.f;
    #pragma unroll 8
    for (int i = 0; i < 32; ++i) {
        float tv = __shfl(xv, i, 64);
        const float4* mp = (const float4*)(M + (size_t)(i0 + i)*DD + js); // 32B aligned
        float4 q0 = mp[0], q1 = mp[1];
        acc[0] += tv*q0.x; acc[1] += tv*q0.y;
        acc[2] += tv*q0.z; acc[3] += tv*q0.w;
        acc[4] += tv*q1.x; acc[5] += tv*q1.y;
        acc[6] += tv*q1.z; acc[7] += tv*q1.w;
    }
    float* dst = ws + (MODE == 0 ? WS_M : (MODE == 1 ? WS_V : WS_G)) + js;
    #pragma unroll
    for (int k = 0; k < 8; ++k) atomicAdd(dst + k, acc[k]);
}

// K5: gate_mid = Wi[:, D:2D] . g ; combine with gate_base; LSTM cell -> new_h.
// Block b: d-range [b*8, b*8+8), wave = gate index.
__global__ __launch_bounds__(256) void k5_gates(
    const float* __restrict__ Wi, const float* __restrict__ curc,
    float* __restrict__ ws)
{
    __shared__ float g_lds[DD];
    __shared__ float gsum[4][8];
    const int t = threadIdx.x, b = blockIdx.x;
    const int wv = t >> 6, lane = t & 63;
    for (int k = 0; k < 8; ++k) {
        int idx = t + k*256;
        g_lds[idx] = ws[WS_G + idx];
    }
    __syncthreads();
    const int d0 = b * 8;
    for (int i = 0; i < 8; ++i) {
        int r = wv*2048 + d0 + i;
        const float* wir = Wi + (size_t)r * INPD + 2048;   // middle slab, 4B aligned
        float acc = 0.f;
        #pragma unroll
        for (int k = 0; k < 32; ++k) {
            int c = k*64 + lane;
            acc += wir[c] * g_lds[c];
        }
        #pragma unroll
        for (int off = 32; off > 0; off >>= 1) acc += __shfl_down(acc, off, 64);
        if (lane == 0) gsum[wv][i] = acc + ws[WS_GB + r];
    }
    __syncthreads();
    if (t < 8) {
        int d = d0 + t;
        float gi = 1.f/(1.f + __expf(-gsum[0][t]));
        float gf = 1.f/(1.f + __expf(-gsum[1][t]));
        float gg = tanhf(gsum[2][t]);
        float go = 1.f/(1.f + __expf(-gsum[3][t]));
        float nc = gf * curc[d] + gi * gg;
        ws[WS_NH + d] = go * tanhf(nc);
    }
}

// K6: out = new_h @ dim_out (262 MB f32). 250 blocks x 128 n's.
// Wave = d-chunk of 512; lane covers 2 adjacent n's via float2 (8B aligned).
__global__ __launch_bounds__(256) void k6_out(
    const float* __restrict__ Dout, const float* __restrict__ ws,
    float* __restrict__ out)
{
    __shared__ float h_lds[DD];
    __shared__ float red[4][128];
    const int t = threadIdx.x, b = blockIdx.x;
    const int wv = t >> 6, lane = t & 63;
    for (int k = 0; k < 8; ++k) h_lds[t + k*256] = ws[WS_NH + t + k*256];
    __syncthreads();
    const int n0 = b * 128;
    const int n  = n0 + lane*2;
    float a0 = 0.f, a1 = 0.f;
    const float2* cp = (const float2*)(Dout + (size_t)(wv*512) * NTOK + n);
    const float*  hp = h_lds + wv*512;
    #pragma unroll 8
    for (int k = 0; k < 512; ++k) {
        float2 q = cp[(size_t)k * (NTOK/2)];
        float h = hp[k];
        a0 += h * q.x;
        a1 += h * q.y;
    }
    red[wv][lane*2]     = a0;
    red[wv][lane*2 + 1] = a1;
    __syncthreads();
    if (t < 128) {
        float s = red[0][t] + red[1][t] + red[2][t] + red[3][t];
        out[n0 + t] = s;
    }
}

extern "C" void kernel_launch(void* const* d_in, const int* in_sizes, int n_in,
                              void* d_out, int out_size, void* d_ws, size_t ws_size,
                              hipStream_t stream)
{
    const float* sen  = (const float*)d_in[0];
    const float* hid  = (const float*)d_in[1];
    const int*   posp = (const int*)d_in[2];
    const float* dup  = (const float*)d_in[3];
    const float* ddn  = (const float*)d_in[4];
    const float* dout = (const float*)d_in[5];
    const float* wgcn = (const float*)d_in[6];
    // d_in[7] att_w: unused — softmax over identical scores is uniform.
    const float* Wi   = (const float*)d_in[8];
    const float* Wh   = (const float*)d_in[9];
    const float* bi   = (const float*)d_in[10];
    const float* bh   = (const float*)d_in[11];
    const float* curh = (const float*)d_in[12];
    const float* curc = (const float*)d_in[13];
    float* ws  = (float*)d_ws;
    float* out = (float*)d_out;

    k1_base<<<dim3(320), dim3(256), 0, stream>>>(sen, hid, posp, Wi, Wh, bi, bh, curh, ws);
    k_mv<0><<<dim3(256), dim3(64), 0, stream>>>(dup,  curh, ws);
    k_mv<1><<<dim3(256), dim3(64), 0, stream>>>(wgcn, curh, ws);
    k_mv<2><<<dim3(256), dim3(64), 0, stream>>>(ddn,  curh, ws);
    k5_gates<<<dim3(256), dim3(256), 0, stream>>>(Wi, curc, ws);
    k6_out<<<dim3(250), dim3(256), 0, stream>>>(dout, ws, out);
}